// Round 1
// baseline (315.375 us; speedup 1.0000x reference)
//
#include <hip/hip_runtime.h>
#include <math.h>

// Masked sparsemax via Michelot's active-set algorithm (no sort).
// One block per row; row data lives in registers across iterations.

constexpr int D   = 2048;
constexpr int TPB = 256;
constexpr int EPT = D / TPB; // 8 elements per thread

__global__ __launch_bounds__(TPB) void sparsemax_kernel(
    const float* __restrict__ x,
    const int*   __restrict__ mask,
    float*       __restrict__ out)
{
    const int    row  = blockIdx.x;
    const int    t    = threadIdx.x;
    const size_t base = (size_t)row * D + (size_t)t * EPT;

    // Coalesced vector loads: 2x float4 + 2x int4 per thread (32 B each stream)
    float4 a  = ((const float4*)(x    + base))[0];
    float4 b  = ((const float4*)(x    + base))[1];
    int4   ma = ((const int4*)  (mask + base))[0];
    int4   mb = ((const int4*)  (mask + base))[1];

    float z[EPT];
    z[0] = ma.x ? a.x : -INFINITY;
    z[1] = ma.y ? a.y : -INFINITY;
    z[2] = ma.z ? a.z : -INFINITY;
    z[3] = ma.w ? a.w : -INFINITY;
    z[4] = mb.x ? b.x : -INFINITY;
    z[5] = mb.y ? b.y : -INFINITY;
    z[6] = mb.z ? b.z : -INFINITY;
    z[7] = mb.w ? b.w : -INFINITY;

    __shared__ float s_red[8];  // 4 wave sums + 4 wave counts
    __shared__ float s_bc[2];   // broadcast S, C

    float theta = -INFINITY;    // first pass: all active entries selected
    float prevC = -1.0f;

    for (int it = 0; it < 128; ++it) {
        float ps = 0.0f, pc = 0.0f;
        #pragma unroll
        for (int k = 0; k < EPT; ++k) {
            if (z[k] > theta) { ps += z[k]; pc += 1.0f; }
        }
        // wave64 reduction
        #pragma unroll
        for (int off = 32; off > 0; off >>= 1) {
            ps += __shfl_down(ps, off, 64);
            pc += __shfl_down(pc, off, 64);
        }
        const int wid = t >> 6;
        if ((t & 63) == 0) { s_red[wid] = ps; s_red[4 + wid] = pc; }
        __syncthreads();
        if (t == 0) {
            s_bc[0] = s_red[0] + s_red[1] + s_red[2] + s_red[3];
            s_bc[1] = s_red[4] + s_red[5] + s_red[6] + s_red[7];
        }
        __syncthreads();
        const float S = s_bc[0];
        const float C = s_bc[1];
        if (C == 0.0f) { theta = INFINITY; break; }  // no active entries -> all zeros
        if (C == prevC) break;                       // set stable -> theta exact
        theta = (S - 1.0f) / C;
        prevC = C;
        // NOTE: no extra __syncthreads needed before next s_red write: the
        // second barrier above guarantees t0 finished reading s_red and all
        // threads finished reading s_bc before any thread re-writes them.
    }

    // p = max(z - theta, 0); masked lanes have z = -inf -> exactly 0.
    float4 o0, o1;
    o0.x = fmaxf(z[0] - theta, 0.0f);
    o0.y = fmaxf(z[1] - theta, 0.0f);
    o0.z = fmaxf(z[2] - theta, 0.0f);
    o0.w = fmaxf(z[3] - theta, 0.0f);
    o1.x = fmaxf(z[4] - theta, 0.0f);
    o1.y = fmaxf(z[5] - theta, 0.0f);
    o1.z = fmaxf(z[6] - theta, 0.0f);
    o1.w = fmaxf(z[7] - theta, 0.0f);
    ((float4*)(out + base))[0] = o0;
    ((float4*)(out + base))[1] = o1;
}

extern "C" void kernel_launch(void* const* d_in, const int* in_sizes, int n_in,
                              void* d_out, int out_size, void* d_ws, size_t ws_size,
                              hipStream_t stream) {
    const float* x    = (const float*)d_in[0];
    const int*   mask = (const int*)  d_in[1];
    float*       out  = (float*)d_out;
    const int n_rows = in_sizes[0] / D;
    sparsemax_kernel<<<n_rows, TPB, 0, stream>>>(x, mask, out);
}